// Round 6
// baseline (289.753 us; speedup 1.0000x reference)
//
#include <hip/hip_runtime.h>

#define HH 128
#define WW 128
#define CC 64
#define LSTR 65          // pad: b128 start-banks 2-way aliased only (free)
#define BS 1024
#define DTC 0.2f

// float offsets into folded-param block (workspace AND its LDS copy)
#define OFF_WG   0
#define OFF_WG1  576
#define OFF_WDX  1152
#define OFF_WDY  1728
#define OFF_BIAS 2304    // [4][64]
#define OFF_SO   2560
#define OFF_BO   2624
#define WS_FLOATS 2688

struct F8 { float4 lo, hi; };
union U8 { F8 v; float a[8]; };

__device__ __forceinline__ F8 ld8(const float* p) {
    F8 r; r.lo = *(const float4*)p; r.hi = *(const float4*)(p + 4); return r;
}
__device__ __forceinline__ void st8(float* p, const F8& v) {
    *(float4*)p = v.lo; *(float4*)(p + 4) = v.hi;
}
__device__ __forceinline__ F8 zero8() {
    F8 r; r.lo = make_float4(0.f,0.f,0.f,0.f); r.hi = r.lo; return r;
}
__device__ __forceinline__ void fma4(float4& a, const float4& x, const float4& wt) {
    a.x = fmaf(x.x, wt.x, a.x); a.y = fmaf(x.y, wt.y, a.y);
    a.z = fmaf(x.z, wt.z, a.z); a.w = fmaf(x.w, wt.w, a.w);
}
__device__ __forceinline__ float4 relu4s(const float4& v, float s) {
    return make_float4(fmaxf(v.x,0.f)*s, fmaxf(v.y,0.f)*s,
                       fmaxf(v.z,0.f)*s, fmaxf(v.w,0.f)*s);
}

// ---------------- pre-kernel: fold BN into conv weights -------------------
__global__ void fold_params(const float* __restrict__ kg,  const float* __restrict__ kg1,
                            const float* __restrict__ kDx, const float* __restrict__ kDy,
                            const float* __restrict__ bng,  const float* __restrict__ bng1,
                            const float* __restrict__ bnDx, const float* __restrict__ bnDy,
                            const float* __restrict__ bn_out,
                            float* __restrict__ wf) {
    const int t = threadIdx.x;        // 256 threads
    const int c = t & 63;
    const int q = t >> 6;             // which conv (0..3)
    const float* K = (q == 0) ? kg  : (q == 1) ? kg1  : (q == 2) ? kDx  : kDy;
    const float* P = (q == 0) ? bng : (q == 1) ? bng1 : (q == 2) ? bnDx : bnDy;
    const float ga = P[c], be = P[64 + c], mu = P[128 + c], va = P[192 + c];
    const float s = ga * rsqrtf(va + 1e-3f);
    const float b = be - mu * s;
    for (int k = 0; k < 9; ++k)
        wf[q * 576 + k * 64 + c] = K[k * 64 + c] * s;
    wf[OFF_BIAS + q * 64 + c] = b;
    if (q == 0) {
        const float ga2 = bn_out[c], be2 = bn_out[64 + c], mu2 = bn_out[128 + c], va2 = bn_out[192 + c];
        const float s2 = ga2 * rsqrtf(va2 + 1e-3f);
        wf[OFF_SO + c] = s2;
        wf[OFF_BO + c] = be2 - mu2 * s2;
    }
}

// ---------------- main fused kernel ---------------------------------------
// Designed to FIT the 64-VGPR budget the compiler pins for wg=1024:
// PDE-resident state = A0, cE(-2ED), 2DBx, 2DBy, D (40) + hreg (8);
// Ax/Ay live in LDS (Lg/Lg1 hold dt*g, dt*g1); all loads in float4 halves.
// amdgpu_num_vgpr(128) is a best-effort budget lift; kernel works without it.
__global__ __launch_bounds__(BS) __attribute__((amdgpu_num_vgpr(128)))
void diffusion_main(
    const float* __restrict__ s0, const float* __restrict__ wf,
    float* __restrict__ out)
{
    __shared__ float Lw[WS_FLOATS];    // 10.5 KB folded params
    __shared__ float Lg [WW * LSTR];   // dt*g   row (Ax)
    __shared__ float Lg1[WW * LSTR];   // dt*g1  row (Ay)
    __shared__ float Lh [WW * LSTR];   // h (=f) row
    __shared__ float Lh2[WW * LSTR];   // h after step 1

    const int t    = threadIdx.x;
    const int w    = t >> 3;          // 0..127
    const int g    = t & 7;           // 8-channel group
    const int cb   = g * 8;           // base channel
    const int lane = t & 63;
    const int bid  = blockIdx.x;
    const int row  = ((bid & 7) << 8) | (bid >> 3);   // XCD swizzle for halo L2 reuse
    const int h    = row & (HH - 1);
    const long rowbase = (long)row * (WW * CC);

    // stage folded params global -> LDS
    for (int i = t; i < WS_FLOATS; i += BS) Lw[i] = wf[i];
    __syncthreads();                                  // (1)

    // ---- conv phase: 4 depthwise 3x3 + BN bias, float4-half FMAs ----
    U8 ag, ag1, adx, ady, hreg;
    ag.v  = ld8(Lw + OFF_BIAS + 0 * 64 + cb);
    ag1.v = ld8(Lw + OFF_BIAS + 1 * 64 + cb);
    adx.v = ld8(Lw + OFF_BIAS + 2 * 64 + cb);
    ady.v = ld8(Lw + OFF_BIAS + 3 * 64 + cb);
    hreg.v = zero8();                                 // will hold f

    #pragma unroll
    for (int dh = -1; dh <= 1; ++dh) {
        const int h2 = h + dh;
        if (h2 >= 0 && h2 < HH) {                     // block-uniform
            const float* rp = s0 + rowbase + (long)dh * (WW * CC);
            #pragma unroll
            for (int dw = -1; dw <= 1; ++dw) {
                const int w2 = w + dw;
                U8 v; v.v = ((unsigned)w2 < WW) ? ld8(rp + w2 * CC + cb) : zero8();
                const int k = (dh + 1) * 3 + (dw + 1);
                const float* wb = Lw + k * 64 + cb;
                {   // lo half: <=16 weight floats in flight
                    fma4(ag.v.lo,  v.v.lo, *(const float4*)(wb + OFF_WG));
                    fma4(ag1.v.lo, v.v.lo, *(const float4*)(wb + OFF_WG1));
                    fma4(adx.v.lo, v.v.lo, *(const float4*)(wb + OFF_WDX));
                    fma4(ady.v.lo, v.v.lo, *(const float4*)(wb + OFF_WDY));
                }
                {   // hi half
                    fma4(ag.v.hi,  v.v.hi, *(const float4*)(wb + OFF_WG  + 4));
                    fma4(ag1.v.hi, v.v.hi, *(const float4*)(wb + OFF_WG1 + 4));
                    fma4(adx.v.hi, v.v.hi, *(const float4*)(wb + OFF_WDX + 4));
                    fma4(ady.v.hi, v.v.hi, *(const float4*)(wb + OFF_WDY + 4));
                }
                if (dh == 0 && dw == 0) hreg = v;     // f
                __builtin_amdgcn_sched_barrier(0);    // cap in-flight per tap
            }
        }
    }
    // scaled activations: Lg=dt*g (Ax), Lg1=dt*g1 (Ay); bx=Bx, by=By in regs
    U8 bx, by;
    {
        F8 ggs, g1s;
        ggs.lo = relu4s(ag.v.lo,  DTC); ggs.hi = relu4s(ag.v.hi,  DTC);
        g1s.lo = relu4s(ag1.v.lo, DTC); g1s.hi = relu4s(ag1.v.hi, DTC);
        bx.v.lo = relu4s(adx.v.lo, DTC); bx.v.hi = relu4s(adx.v.hi, DTC);
        by.v.lo = relu4s(ady.v.lo, DTC); by.v.hi = relu4s(ady.v.hi, DTC);
        st8(Lg  + w * LSTR + cb, ggs);
        st8(Lg1 + w * LSTR + cb, g1s);
        st8(Lh  + w * LSTR + cb, hreg.v);             // h starts as f
    }
    __syncthreads();                                  // (2)

    const int wm = (w + WW - 1) & (WW - 1);
    const int wp = (w + 1) & (WW - 1);
    const int lm = (g == 0) ? lane + 7 : lane - 1;    // lane holding channel cb-1
    const int lp = (g == 7) ? lane - 7 : lane + 1;    // lane holding channel cb+8

    // ---- transition: A0, cE, 2DBx, 2DBy, D (h0 == f for K=2) ----
    U8 A0u, cEu, Du;                                  // bx,by become 2DBx,2DBy in place
    #pragma unroll
    for (int hx = 0; hx < 2; ++hx) {
        const int k0 = hx * 4;
        const float4 am = *(const float4*)(Lg + wm * LSTR + cb + k0);  // dt*g[w-1]
        const float4 ap = *(const float4*)(Lg + wp * LSTR + cb + k0);  // dt*g[w+1]
        #pragma unroll
        for (int j = 0; j < 4; ++j) {
            const int k = k0 + j;
            const int c = cb + k;
            const float vm = Lg1[w * LSTR + ((c + 63) & 63)];          // dt*g1[c-1]
            const float vp = Lg1[w * LSTR + ((c + 1) & 63)];           // dt*g1[c+1]
            // E = dt*(ux+vy); Lg/Lg1 already carry dt
            const float E = 0.5f * ((((const float*)&am)[j] - ((const float*)&ap)[j]) + (vm - vp));
            const float den = 1.f + 2.f * bx.a[k] + 2.f * by.a[k];
            const float D = __builtin_amdgcn_rcpf(den);
            Du.a[k]  = D;
            A0u.a[k] = hreg.a[k] * ((2.f + 2.f * DTC) * D - 1.f);      // D*f*(1-2Bx-2By+2dt)
            cEu.a[k] = -2.f * E * D;
            bx.a[k]  = 2.f * D * bx.a[k];
            by.a[k]  = 2.f * D * by.a[k];
        }
    }

    // ---- PDE step: h' = A0 + cE*h + 2DBx*(hwm+hwp) + 2DBy*(hcm+hcp)
    //                   + D*( dtg*(hwp-hwm) + dtg1*(hcp-hcm) )
    auto pde = [&](const float* Lsrc, float* Ldst, bool store) {
        const float em = __shfl(hreg.v.hi.w, lm);     // old h[c-1] for field 0
        const float ep = __shfl(hreg.v.lo.x, lp);     // old h[c+1] for field 7
        float prev = em;                              // rolling old h[k-1]
        #pragma unroll
        for (int hx = 0; hx < 2; ++hx) {
            const int k0 = hx * 4;
            const float4 hm4 = *(const float4*)(Lsrc + wm * LSTR + cb + k0);
            const float4 hp4 = *(const float4*)(Lsrc + wp * LSTR + cb + k0);
            const float4 ga4 = *(const float4*)(Lg  + w * LSTR + cb + k0);
            const float4 gb4 = *(const float4*)(Lg1 + w * LSTR + cb + k0);
            #pragma unroll
            for (int j = 0; j < 4; ++j) {
                const int k = k0 + j;
                const float cur = hreg.a[k];
                const float nxt = (k == 7) ? ep : hreg.a[k + 1];   // old h[k+1]
                const float hm = ((const float*)&hm4)[j];
                const float hp = ((const float*)&hp4)[j];
                const float s  = hm + hp,  dv = hp - hm;
                const float sc = prev + nxt, dc = nxt - prev;
                float acc = fmaf(cEu.a[k], cur, A0u.a[k]);
                acc = fmaf(bx.a[k], s,  acc);
                acc = fmaf(by.a[k], sc, acc);
                float u = ((const float*)&ga4)[j] * dv;
                u = fmaf(((const float*)&gb4)[j], dc, u);
                acc = fmaf(Du.a[k], u, acc);
                hreg.a[k] = acc;
                prev = cur;
            }
        }
        if (store) st8(Ldst + w * LSTR + cb, hreg.v);
    };

    pde(Lh, Lh2, true);       // step 1: read f-row, write Lh2
    __syncthreads();          // (3) Lh2 visible
    pde(Lh2, Lh2, false);     // step 2: read Lh2, result stays in hreg

    // ---- epilogue: out-BN + ReLU ----
    {
        const F8 so = ld8(Lw + OFF_SO + cb);
        const F8 bo = ld8(Lw + OFF_BO + cb);
        U8 o;
        #pragma unroll
        for (int k = 0; k < 8; ++k)
            o.a[k] = fmaxf(fmaf(hreg.a[k], ((const U8&)so).a[k], ((const U8&)bo).a[k]), 0.f);
        st8(out + rowbase + w * CC + cb, o.v);
    }
}

extern "C" void kernel_launch(void* const* d_in, const int* in_sizes, int n_in,
                              void* d_out, int out_size, void* d_ws, size_t ws_size,
                              hipStream_t stream) {
    const float* s0   = (const float*)d_in[0];
    const float* kg   = (const float*)d_in[1];
    const float* kg1  = (const float*)d_in[2];
    const float* kDx  = (const float*)d_in[3];
    const float* kDy  = (const float*)d_in[4];
    const float* bng  = (const float*)d_in[5];
    const float* bng1 = (const float*)d_in[6];
    const float* bnDx = (const float*)d_in[7];
    const float* bnDy = (const float*)d_in[8];
    const float* bno  = (const float*)d_in[9];
    float* out = (float*)d_out;
    float* wf  = (float*)d_ws;   // WS_FLOATS floats

    fold_params<<<1, 256, 0, stream>>>(kg, kg1, kDx, kDy,
                                       bng, bng1, bnDx, bnDy, bno, wf);
    diffusion_main<<<dim3(16 * 128), dim3(BS), 0, stream>>>(s0, wf, out);
}